// Round 3
// baseline (6559.881 us; speedup 1.0000x reference)
//
#include <hip/hip_runtime.h>
#include <math.h>

#define NTHR 1024   // threads per block (2 threads per point)
#define DD   128    // feature dim
#define HD   64     // dims per thread

typedef unsigned long long ull;

// packed argmax key: (ordered f32)<<32 | ~idx  -> max() gives argmax with
// smallest-index tie-break, matching jnp.argmax first-occurrence.
__device__ __forceinline__ ull pkkey(float f, unsigned idx) {
  unsigned u = __float_as_uint(f);
  u = (u & 0x80000000u) ? ~u : (u | 0x80000000u);
  return ((ull)u << 32) | (ull)(~idx);
}

__device__ __forceinline__ ull wredmax(ull v) {
#pragma unroll
  for (int m = 32; m; m >>= 1) {
    ull o = __shfl_xor(v, m, 64);
    v = (o > v) ? o : v;
  }
  return v;
}

// Fused {block argmax -> tagged slot store -> all-blocks poll -> local reduce}.
// Slot format: f32bits<<32 | (t+1)<<17 | idx   (idx < 2^17, tag fits 15 bits;
// memset-0 init never matches). Double-buffered by t&1.
__device__ __forceinline__ int roundSync(float val, unsigned pidx, int t,
                                         ull* __restrict__ partials, int nblk,
                                         ull* s_w, ull* s_r,
                                         int tid, int lane, int wid, int blockId) {
  ull key = wredmax(pkkey(val, pidx));
  if (lane == 0) s_w[wid] = key;
  __syncthreads();
  if (tid == 0) {
    ull m = s_w[0];
#pragma unroll
    for (int i = 1; i < NTHR / 64; ++i) { ull o = s_w[i]; if (o > m) m = o; }
    unsigned idx = ~(unsigned)m;  // low word was ~idx
    ull slotv = (m & 0xFFFFFFFF00000000ull) | ((ull)(unsigned)(t + 1) << 17) | (ull)idx;
    __hip_atomic_store(&partials[(t & 1) * nblk + blockId], slotv,
                       __ATOMIC_RELEASE, __HIP_MEMORY_SCOPE_AGENT);
  }
  // poll all slots in parallel (one per thread), with sleep backoff so the
  // fabric isn't flooded while leaders' stores propagate
  ull ck = 0;
  if (tid < nblk) {
    ull* slot = &partials[(t & 1) * nblk + tid];
    const unsigned tag = (unsigned)(t + 1);
    ull v = __hip_atomic_load(slot, __ATOMIC_ACQUIRE, __HIP_MEMORY_SCOPE_AGENT);
    while (((unsigned)(v >> 17) & 0x7FFFu) != tag) {
      __builtin_amdgcn_s_sleep(8);
      v = __hip_atomic_load(slot, __ATOMIC_ACQUIRE, __HIP_MEMORY_SCOPE_AGENT);
    }
    unsigned idx = (unsigned)v & 0x1FFFFu;
    ck = (v & 0xFFFFFFFF00000000ull) | (ull)(~idx);
  }
  ck = wredmax(ck);
  if (lane == 0) s_r[wid] = ck;
  __syncthreads();
  ull m = s_r[0];
#pragma unroll
  for (int i = 1; i < NTHR / 64; ++i) { ull o = s_r[i]; if (o > m) m = o; }
  return (int)(~(unsigned)m);
}

// stage normalized selected row into LDS (f32 squares, exact f64 sum, f32 sqrt, IEEE f32 div)
// feat is read-only -> plain cached loads are coherence-safe.
__device__ __forceinline__ void stage(const float* __restrict__ feat, int c,
                                      float* s_sel, float* s_nrm, int tid, int lane) {
  const float* __restrict__ row = feat + (size_t)c * DD;
  if (tid < 64) {
    float x1 = row[lane], x2 = row[lane + 64];
    double s = (double)(x1 * x1) + (double)(x2 * x2);
#pragma unroll
    for (int m = 32; m; m >>= 1) s += __shfl_xor(s, m, 64);
    if (lane == 0) *s_nrm = fmaxf(sqrtf((float)s), 1e-12f);
  }
  __syncthreads();
  const float nm = *s_nrm;
  if (tid < DD) s_sel[tid] = row[tid] / nm;
  __syncthreads();
}

// distance of my point (half-row in regs) to staged row; pair halves combined via shfl
__device__ __forceinline__ float distTo(const float4* pv, const float* s_sel, int half) {
  const float4* sp = reinterpret_cast<const float4*>(s_sel) + half * (HD / 4);
  double a0 = 0.0, a1 = 0.0, a2 = 0.0, a3 = 0.0;
#pragma unroll
  for (int j = 0; j < HD / 4; ++j) {
    float4 v = pv[j], c = sp[j];
    float d0 = v.x - c.x, d1 = v.y - c.y, d2 = v.z - c.z, d3 = v.w - c.w;
    a0 += (double)(d0 * d0); a1 += (double)(d1 * d1);
    a2 += (double)(d2 * d2); a3 += (double)(d3 * d3);
  }
  double s = (a0 + a1) + (a2 + a3);
  s += __shfl_xor(s, 1, 64);   // combine the pair's halves (exact to ~2^-52)
  return sqrtf((float)s);
}

__global__ __launch_bounds__(NTHR, 2)   // 2nd arg lifts VGPR cap to 256; still 1 blk/CU
void fps_kernel(const float* __restrict__ feat, const float* __restrict__ att,
                const int* __restrict__ kptr, int* __restrict__ out,
                ull* __restrict__ partials, int N, int nblk) {
  __shared__ ull s_w[NTHR / 64];
  __shared__ ull s_r[NTHR / 64];
  __shared__ alignas(16) float s_sel[DD];
  __shared__ float s_nrm;

  const int tid  = threadIdx.x;
  const int lane = tid & 63;
  const int wid  = tid >> 6;
  const int gid  = blockIdx.x * NTHR + tid;
  const int pidx = gid >> 1;   // point index (2 threads per point)
  const int half = tid & 1;    // which 64-dim half this thread owns
  const int k    = kptr[0];

  if (k >= N) {  // reference returns arange(N)
    for (int i = gid; i < N; i += nblk * NTHR) out[i] = i;
    return;
  }

  // ---- load my 64-dim half into VGPRs (coalesced: addr = gid*64*4B)
  const float* __restrict__ base = feat + (size_t)gid * HD;
  float4 pv[HD / 4];
#pragma unroll
  for (int j = 0; j < HD / 4; ++j) pv[j] = reinterpret_cast<const float4*>(base)[j];

  // ---- L2-normalize (f32 squares, exact f64 sum across both halves)
  {
    double a0 = 0.0, a1 = 0.0, a2 = 0.0, a3 = 0.0;
#pragma unroll
    for (int j = 0; j < HD / 4; ++j) {
      float4 v = pv[j];
      a0 += (double)(v.x * v.x); a1 += (double)(v.y * v.y);
      a2 += (double)(v.z * v.z); a3 += (double)(v.w * v.w);
    }
    double s = (a0 + a1) + (a2 + a3);
    s += __shfl_xor(s, 1, 64);
    float nm = fmaxf(sqrtf((float)s), 1e-12f);
#pragma unroll
    for (int j = 0; j < HD / 4; ++j) {
      pv[j].x /= nm; pv[j].y /= nm; pv[j].z /= nm; pv[j].w /= nm;
      // Pin in VGPRs: "modifying" the values makes remat-from-global illegal,
      // so the compiler must keep them live in registers across the round loop.
      asm volatile("" : "+v"(pv[j].x), "+v"(pv[j].y), "+v"(pv[j].z), "+v"(pv[j].w));
    }
  }

  // ---- phase A: argmax(attention_scores)
  int far = roundSync(att[pidx], (unsigned)pidx, 0, partials, nblk,
                      s_w, s_r, tid, lane, wid, blockIdx.x);
  if (gid == 0) out[0] = far;

  stage(feat, far, s_sel, &s_nrm, tid, lane);
  float mind = distTo(pv, s_sel, half);
  if (pidx == far) mind = -__builtin_inff();

  // ---- main FPS loop
  for (int t = 1; t < k; ++t) {
    far = roundSync(mind, (unsigned)pidx, t, partials, nblk,
                    s_w, s_r, tid, lane, wid, blockIdx.x);
    if (gid == 0) out[t] = far;

    stage(feat, far, s_sel, &s_nrm, tid, lane);
    float d = distTo(pv, s_sel, half);
    mind = fminf(mind, d);
    if (pidx == far) mind = -__builtin_inff();
  }
}

extern "C" void kernel_launch(void* const* d_in, const int* in_sizes, int n_in,
                              void* d_out, int out_size, void* d_ws, size_t ws_size,
                              hipStream_t stream) {
  const float* feat = (const float*)d_in[0];
  const float* att  = (const float*)d_in[1];
  const int*   kptr = (const int*)d_in[2];
  int* out = (int*)d_out;

  const int N    = in_sizes[1];        // 131072
  const int nblk = (2 * N) / NTHR;     // 256 blocks -> 1 per CU, all co-resident

  ull* partials = (ull*)d_ws;
  // zero the tagged slots every call (graph-replay determinism; tag>=1 never matches 0)
  hipMemsetAsync(d_ws, 0, (size_t)(2 * nblk * sizeof(ull)), stream);
  fps_kernel<<<nblk, NTHR, 0, stream>>>(feat, att, kptr, out, partials, N, nblk);
}